// Round 7
// baseline (724.976 us; speedup 1.0000x reference)
//
#include <hip/hip_runtime.h>

#define D 128
#define N_SRC 100000
#define N_DST 100000
#define N_EDGES 640000

#define SCAN_BLK 1024
#define N_SCAN_BLOCKS ((N_DST + SCAN_BLK - 1) / SCAN_BLK)   // 98

#define CSR_BLOCKS 1024
#define CSR_THREADS (CSR_BLOCKS * 256)                      // 262144

typedef __attribute__((ext_vector_type(8))) short s8v;
typedef __attribute__((ext_vector_type(4))) float f32x4;

__device__ __forceinline__ unsigned short f2bf(float f) {
    unsigned int u = __float_as_uint(f);
    u += 0x7fffu + ((u >> 16) & 1u);   // round-to-nearest-even
    return (unsigned short)(u >> 16);
}

__device__ __forceinline__ unsigned int pk2(float a, float b) {
    return (unsigned int)f2bf(a) | ((unsigned int)f2bf(b) << 16);
}

// Device-scope grid barrier. Safe because grid (1024 blocks) is exactly the
// guaranteed-resident capacity: __launch_bounds__(256,4) caps VGPR at 128
// -> 4 blocks/CU x 256 CUs. Agent-scope release/acquire handles cross-XCD
// L2 visibility for the plain stores before/after.
__device__ __forceinline__ void grid_barrier(int* ctr) {
    __syncthreads();
    if (threadIdx.x == 0) {
        __threadfence();
        __hip_atomic_fetch_add(ctr, 1, __ATOMIC_RELEASE, __HIP_MEMORY_SCOPE_AGENT);
        while (__hip_atomic_load(ctr, __ATOMIC_ACQUIRE, __HIP_MEMORY_SCOPE_AGENT)
               < CSR_BLOCKS) {}
    }
    __syncthreads();
}

// ---- build_csr: zero+cvt+packW | hist | scan | offsets | scatter --------
// One dispatch replaces prep / scan_blocks / add_offsets / scatter_perm.
__global__ __launch_bounds__(256, 4) void build_csr(
    const float* __restrict__ h_src,
    const int* __restrict__ src_idx, const int* __restrict__ dst_idx,
    const float* __restrict__ W,
    unsigned int* __restrict__ mir32, unsigned short* __restrict__ Bp,
    int* __restrict__ counts, int* __restrict__ row_start,
    int* __restrict__ cursor, int* __restrict__ block_sums,
    int* __restrict__ edge_src, int* __restrict__ bar)
{
    __shared__ int sh[256];
    const int tid = threadIdx.x;
    const int gid = blockIdx.x * 256 + tid;

    // ---- Phase A: zero counts; h_src -> bf16 mirror; pack W
    for (int i = gid; i < N_DST; i += CSR_THREADS) counts[i] = 0;
    for (int id = gid; id < N_SRC * 16; id += CSR_THREADS) {
        const float4* p = (const float4*)(h_src + (size_t)id * 8);
        float4 x = p[0], y = p[1];
        uint4 o;
        o.x = pk2(x.x, x.y); o.y = pk2(x.z, x.w);
        o.z = pk2(y.x, y.y); o.w = pk2(y.z, y.w);
        *(uint4*)(mir32 + (size_t)(id >> 4) * 64 + (id & 15) * 4) = o;
    }
    for (int id = gid; id < 32768; id += CSR_THREADS) {
        int j = id & 7;
        int l = (id >> 3) & 63;
        int t = (id >> 9) & 7;
        int s = id >> 12;
        int k = s * 32 + (l >> 4) * 8 + j;
        int n = t * 16 + (l & 15);
        Bp[id] = f2bf(W[k * D + n]);
    }
    grid_barrier(&bar[0]);

    // ---- Phase B: histogram
    for (int e = gid; e < N_EDGES; e += CSR_THREADS)
        atomicAdd(&counts[dst_idx[e]], 1);
    grid_barrier(&bar[1]);

    // ---- Phase C: per-1024-chunk exclusive prescan (blocks 0..97)
    if (blockIdx.x < N_SCAN_BLOCKS) {
        const int base = blockIdx.x * SCAN_BLK + tid * 4;
        int v[4];
        int local = 0;
#pragma unroll
        for (int k = 0; k < 4; k++) {
            int idx = base + k;
            v[k] = (idx < N_DST) ? counts[idx] : 0;
            local += v[k];
        }
        sh[tid] = local;
        __syncthreads();
        for (int off = 1; off < 256; off <<= 1) {
            int t = (tid >= off) ? sh[tid - off] : 0;
            __syncthreads();
            sh[tid] += t;
            __syncthreads();
        }
        int run = (tid == 0) ? 0 : sh[tid - 1];
        if (tid == 255) block_sums[blockIdx.x] = sh[255];
#pragma unroll
        for (int k = 0; k < 4; k++) {
            int idx = base + k;
            if (idx < N_DST) row_start[idx] = run;
            run += v[k];
        }
    }
    grid_barrier(&bar[2]);

    // ---- Phase D: top-scan of 98 sums (redundant per block) + add offsets
    if (tid < 128) sh[tid] = (tid < N_SCAN_BLOCKS) ? block_sums[tid] : 0;
    __syncthreads();
    for (int off = 1; off < 128; off <<= 1) {
        int t = (tid < 128 && tid >= off) ? sh[tid - off] : 0;
        __syncthreads();
        if (tid < 128) sh[tid] += t;
        __syncthreads();
    }
    for (int i = gid; i < N_DST; i += CSR_THREADS) {
        int blk = i / SCAN_BLK;
        int off = (blk == 0) ? 0 : sh[blk - 1];
        int v = row_start[i] + off;
        row_start[i] = v;
        cursor[i] = v;
    }
    if (gid == 0) row_start[N_DST] = N_EDGES;
    grid_barrier(&bar[3]);

    // ---- Phase E: scatter edges into CSR order
    for (int e = gid; e < N_EDGES; e += CSR_THREADS) {
        int d = dst_idx[e];
        int pos = atomicAdd(&cursor[d], 1);
        edge_src[pos] = src_idx[e];
    }
}

// ================== FUSED gather + projection ============================
// 256-thread blocks, 4 waves x 16 rows = 64 rows/block, 1563 blocks.
// Per wave: gather its 16 rows of h_N from the dense bf16 mirror into its
// own LDS slice (in-wave dep only, no __syncthreads), then MFMA-project
// with B fragments read per-wave from L2 (Bp 64 KB, L2-hot). Edge ids via
// per-lane same-address loads (HW broadcast) instead of shfl: shorter
// dependency chain. Full batches take the unmasked fast path.
__global__ __launch_bounds__(256, 4) void fused_ag(
    const float* __restrict__ h_dst,
    const unsigned short* __restrict__ mir,   // dense [N_SRC][128] bf16
    const int* __restrict__ row_start,
    const int* __restrict__ edge_src,
    const unsigned short* __restrict__ Bp,
    const float* __restrict__ bias,
    float* __restrict__ out)
{
    __shared__ uint4 hN4[1024];              // 16 KB: h_N[64 rows][256 B]
    char* hN = (char*)hN4;

    const int tid = threadIdx.x;
    const int wave = tid >> 6;               // 0..3
    const int lane = tid & 63;
    const int quad = lane >> 4;
    const int lr = lane & 15;
    const int wg = blockIdx.x * 4 + wave;    // global wave id
    if (wg * 16 >= N_DST) return;            // no barriers below: safe
    const int rw0 = wg * 16;                 // wave's first row

    // ---- gather: 4 iterations x 4 rows (one row per 16-lane quad)
#pragma unroll
    for (int i = 0; i < 4; i++) {
        int rl = wave * 16 + i * 4 + quad;          // local row 0..63
        int row = blockIdx.x * 64 + rl;             // == rw0 + i*4 + quad
        int start = row_start[row];
        int deg = row_start[row + 1] - start;
        int nfull = deg & ~7;
        float a[8] = {0.f, 0.f, 0.f, 0.f, 0.f, 0.f, 0.f, 0.f};
        for (int base = 0; base < nfull; base += 8) {
#pragma unroll
            for (int t = 0; t < 8; t++) {
                int s = edge_src[start + base + t];   // same addr: HW bcast
                uint4 u = *(const uint4*)(mir + (size_t)s * 128 + lr * 8);
                a[0] += __uint_as_float(u.x << 16);
                a[1] += __uint_as_float(u.x & 0xffff0000u);
                a[2] += __uint_as_float(u.y << 16);
                a[3] += __uint_as_float(u.y & 0xffff0000u);
                a[4] += __uint_as_float(u.z << 16);
                a[5] += __uint_as_float(u.z & 0xffff0000u);
                a[6] += __uint_as_float(u.w << 16);
                a[7] += __uint_as_float(u.w & 0xffff0000u);
            }
        }
        if (nfull < deg) {
#pragma unroll
            for (int t = 0; t < 8; t++) {
                int s = edge_src[start + min(nfull + t, deg - 1)];
                uint4 u = *(const uint4*)(mir + (size_t)s * 128 + lr * 8);
                float m = ((nfull + t) < deg) ? 1.f : 0.f;
                a[0] = fmaf(__uint_as_float(u.x << 16), m, a[0]);
                a[1] = fmaf(__uint_as_float(u.x & 0xffff0000u), m, a[1]);
                a[2] = fmaf(__uint_as_float(u.y << 16), m, a[2]);
                a[3] = fmaf(__uint_as_float(u.y & 0xffff0000u), m, a[3]);
                a[4] = fmaf(__uint_as_float(u.z << 16), m, a[4]);
                a[5] = fmaf(__uint_as_float(u.z & 0xffff0000u), m, a[5]);
                a[6] = fmaf(__uint_as_float(u.w << 16), m, a[6]);
                a[7] = fmaf(__uint_as_float(u.w & 0xffff0000u), m, a[7]);
            }
        }
        float inv = 1.0f / fmaxf((float)deg, 1.0f);
        uint4 o;
        o.x = pk2(a[0] * inv, a[1] * inv);
        o.y = pk2(a[2] * inv, a[3] * inv);
        o.z = pk2(a[4] * inv, a[5] * inv);
        o.w = pk2(a[6] * inv, a[7] * inv);
        // XOR swizzle (bits 4-6) -> max 2-way conflict on the frag reads
        int ba = (rl * 256 + lr * 16) ^ ((rl & 7) << 4);
        *(uint4*)(hN + ba) = o;
    }

    // ---- read back own h_N fragments (in-wave LDS dep; compiler waits)
    s8v an[4];
    {
        int rl = wave * 16 + lr;
#pragma unroll
        for (int s = 0; s < 4; s++) {
            int ba = (rl * 256 + s * 64 + quad * 16) ^ ((rl & 7) << 4);
            an[s] = *(const s8v*)(hN + ba);
        }
    }

    // ---- h_dst loads + convert to bf16 A fragments
    const int r0 = rw0 + lr;
    const float* p0 = h_dst + (size_t)r0 * D + quad * 8;
    float4 x0[4], y0[4];
#pragma unroll
    for (int s = 0; s < 4; s++) {
        x0[s] = *(const float4*)(p0 + s * 32);
        y0[s] = *(const float4*)(p0 + s * 32 + 4);
    }
    s8v af0[4];
#pragma unroll
    for (int s = 0; s < 4; s++) {
        unsigned short u0[8];
        u0[0]=f2bf(x0[s].x); u0[1]=f2bf(x0[s].y); u0[2]=f2bf(x0[s].z); u0[3]=f2bf(x0[s].w);
        u0[4]=f2bf(y0[s].x); u0[5]=f2bf(y0[s].y); u0[6]=f2bf(y0[s].z); u0[7]=f2bf(y0[s].w);
        af0[s] = *(s8v*)u0;
    }

    f32x4 acc[8];
#pragma unroll
    for (int t = 0; t < 8; t++) acc[t] = (f32x4){0.f, 0.f, 0.f, 0.f};

    // ---- MFMA: K=0..127 from h_dst frags, K=128..255 from h_N frags
#pragma unroll
    for (int s = 0; s < 8; s++) {
        s8v a0 = (s < 4) ? af0[s] : an[s - 4];
#pragma unroll
        for (int t = 0; t < 8; t++) {
            s8v bf = *(const s8v*)(Bp + ((size_t)(s * 8 + t) * 64 + lane) * 8);
            acc[t] = __builtin_amdgcn_mfma_f32_16x16x32_bf16(a0, bf, acc[t], 0, 0, 0);
        }
    }

    // ---- epilogue (N_DST % 16 == 0: wave's rows all valid)
#pragma unroll
    for (int t = 0; t < 8; t++) {
        float bv = bias[t * 16 + lr];
#pragma unroll
        for (int r = 0; r < 4; r++) {
            int row = rw0 + quad * 4 + r;
            out[(size_t)row * D + t * 16 + lr] = acc[t][r] + bv;
        }
    }
}

extern "C" void kernel_launch(void* const* d_in, const int* in_sizes, int n_in,
                              void* d_out, int out_size, void* d_ws, size_t ws_size,
                              hipStream_t stream) {
    const float* h_src  = (const float*)d_in[0];
    const float* h_dst  = (const float*)d_in[1];
    const int* src_idx  = (const int*)d_in[2];
    const int* dst_idx  = (const int*)d_in[3];
    const float* W      = (const float*)d_in[4];
    const float* b      = (const float*)d_in[5];
    float* out = (float*)d_out;

    // Workspace: Bp | CSR ints | barrier | edge_src | dense bf16 mirror
    unsigned short* Bp = (unsigned short*)d_ws;         // 32768 u16 = 64 KB
    int* ws_i          = (int*)((char*)d_ws + 65536);
    int* row_start     = ws_i;                          // N_DST+1
    int* cursor        = row_start + (N_DST + 1);       // N_DST
    int* counts        = cursor + N_DST;                // N_DST
    int* block_sums    = counts + N_DST;                // N_SCAN_BLOCKS
    int* bar           = block_sums + N_SCAN_BLOCKS;    // 8
    int* edge_src      = bar + 8;                       // N_EDGES

    size_t int_bytes = (size_t)(N_DST + 1 + N_DST + N_DST + N_SCAN_BLOCKS + 8
                                + N_EDGES) * 4;
    size_t mir_off   = (65536 + int_bytes + 255) & ~(size_t)255;
    unsigned short* mir = (unsigned short*)((char*)d_ws + mir_off);

    // Only the barrier words need zeroing; counts are zeroed in-kernel.
    hipMemsetAsync(bar, 0, 8 * sizeof(int), stream);

    build_csr<<<CSR_BLOCKS, 256, 0, stream>>>(
        h_src, src_idx, dst_idx, W,
        (unsigned int*)mir, Bp,
        counts, row_start, cursor, block_sums, edge_src, bar);

    fused_ag<<<(N_DST + 63) / 64, 256, 0, stream>>>(
        h_dst, mir, row_start, edge_src, Bp, b, out);
}

// Round 8
// 257.715 us; speedup vs baseline: 2.8131x; 2.8131x over previous
//
#include <hip/hip_runtime.h>

#define D 128
#define N_SRC 100000
#define N_DST 100000
#define N_EDGES 640000

#define SCAN_BLK 1024
#define N_SCAN_BLOCKS ((N_DST + SCAN_BLK - 1) / SCAN_BLK)   // 98

#define SCAT_BLOCKS ((N_EDGES + 255) / 256)                 // 2500
#define CVT_BLOCKS  ((N_SRC * D / 8) / 256)                 // 6250 (exact)
#define PACKW_BLOCKS 128

typedef __attribute__((ext_vector_type(8))) short s8v;
typedef __attribute__((ext_vector_type(4))) float f32x4;

__device__ __forceinline__ unsigned short f2bf(float f) {
    unsigned int u = __float_as_uint(f);
    u += 0x7fffu + ((u >> 16) & 1u);   // round-to-nearest-even
    return (unsigned short)(u >> 16);
}

__device__ __forceinline__ unsigned int pk2(float a, float b) {
    return (unsigned int)f2bf(a) | ((unsigned int)f2bf(b) << 16);
}

// ---- hist: critical-path head, nothing else bundled ---------------------
__global__ __launch_bounds__(256) void hist_kernel(
    const int* __restrict__ dst_idx, int* __restrict__ counts)
{
    int e = blockIdx.x * 256 + threadIdx.x;
    if (e < N_EDGES) atomicAdd(&counts[dst_idx[e]], 1);
}

__global__ __launch_bounds__(256) void scan_blocks(
    const int* __restrict__ counts, int* __restrict__ row_start,
    int* __restrict__ block_sums)
{
    __shared__ int sh[256];
    const int tid = threadIdx.x;
    const int base = blockIdx.x * SCAN_BLK + tid * 4;
    int v[4];
    int local = 0;
#pragma unroll
    for (int k = 0; k < 4; k++) {
        int idx = base + k;
        v[k] = (idx < N_DST) ? counts[idx] : 0;
        local += v[k];
    }
    sh[tid] = local;
    __syncthreads();
    for (int off = 1; off < 256; off <<= 1) {
        int t = (tid >= off) ? sh[tid - off] : 0;
        __syncthreads();
        sh[tid] += t;
        __syncthreads();
    }
    int run = (tid == 0) ? 0 : sh[tid - 1];
    if (tid == 255) block_sums[blockIdx.x] = sh[255];
#pragma unroll
    for (int k = 0; k < 4; k++) {
        int idx = base + k;
        if (idx < N_DST) row_start[idx] = run;
        run += v[k];
    }
}

// top-scan of the 98 block sums done redundantly per block in LDS.
__global__ __launch_bounds__(256) void add_offsets(
    int* __restrict__ row_start, const int* __restrict__ block_sums,
    int* __restrict__ cursor)
{
    __shared__ int sh[128];
    const int tid = threadIdx.x;
    if (tid < 128) sh[tid] = (tid < N_SCAN_BLOCKS) ? block_sums[tid] : 0;
    __syncthreads();
    for (int off = 1; off < 128; off <<= 1) {
        int t = (tid < 128 && tid >= off) ? sh[tid - off] : 0;
        __syncthreads();
        if (tid < 128) sh[tid] += t;
        __syncthreads();
    }
    int i = blockIdx.x * 256 + tid;
    if (i < N_DST) {
        int blk = i / SCAN_BLK;
        int off = (blk == 0) ? 0 : sh[blk - 1];
        int v = row_start[i] + off;
        row_start[i] = v;
        cursor[i] = v;
    }
    if (i == 0) row_start[N_DST] = N_EDGES;
}

// ---- scatter + cvt + packW in ONE launch --------------------------------
// scatter is latency-bound (random atomic scatter: machine mostly idle);
// cvt is BW-bound streaming and independent of the CSR chain -> riding it
// here fills the idle issue slots instead of serializing ahead of scan.
__global__ __launch_bounds__(256) void scatter_cvt(
    const int* __restrict__ src_idx, const int* __restrict__ dst_idx,
    int* __restrict__ cursor, int* __restrict__ edge_src,
    const float* __restrict__ h_src, unsigned int* __restrict__ mir32,
    const float* __restrict__ W, unsigned short* __restrict__ Bp)
{
    const int blk = blockIdx.x;
    const int tid = threadIdx.x;
    if (blk < SCAT_BLOCKS) {
        int e = blk * 256 + tid;
        if (e < N_EDGES) {
            int d = dst_idx[e];
            int pos = atomicAdd(&cursor[d], 1);
            edge_src[pos] = src_idx[e];
        }
    } else if (blk < SCAT_BLOCKS + CVT_BLOCKS) {
        int id = (blk - SCAT_BLOCKS) * 256 + tid;      // [0, 1.6e6)
        const float4* p = (const float4*)(h_src + (size_t)id * 8);
        float4 x = p[0], y = p[1];
        uint4 o;
        o.x = pk2(x.x, x.y); o.y = pk2(x.z, x.w);
        o.z = pk2(y.x, y.y); o.w = pk2(y.z, y.w);
        // dense mirror: row r = id>>4, 64 u32 per row
        *(uint4*)(mir32 + (size_t)(id >> 4) * 64 + (id & 15) * 4) = o;
    } else {
        // pack W into MFMA B-fragment order (bf16)
        int id = (blk - SCAT_BLOCKS - CVT_BLOCKS) * 256 + tid;
        if (id < 32768) {
            int j = id & 7;
            int l = (id >> 3) & 63;
            int t = (id >> 9) & 7;
            int s = id >> 12;
            int k = s * 32 + (l >> 4) * 8 + j;
            int n = t * 16 + (l & 15);
            Bp[id] = f2bf(W[k * D + n]);
        }
    }
}

// ================== FUSED gather + projection (R6, unchanged) ============
// 256-thread blocks, 4 waves x 16 rows = 64 rows/block, 1563 blocks.
// Per wave: gather its 16 rows of h_N from the dense bf16 mirror into its
// own LDS slice (in-wave dep only, no __syncthreads), then MFMA-project
// with B fragments read per-wave from L2 (Bp 64 KB, L2-hot).
__global__ __launch_bounds__(256, 4) void fused_ag(
    const float* __restrict__ h_dst,
    const unsigned short* __restrict__ mir,   // dense [N_SRC][128] bf16
    const int* __restrict__ row_start,
    const int* __restrict__ edge_src,
    const unsigned short* __restrict__ Bp,
    const float* __restrict__ bias,
    float* __restrict__ out)
{
    __shared__ uint4 hN4[1024];              // 16 KB: h_N[64 rows][256 B]
    char* hN = (char*)hN4;

    const int tid = threadIdx.x;
    const int wave = tid >> 6;               // 0..3
    const int lane = tid & 63;
    const int quad = lane >> 4;
    const int lr = lane & 15;
    const int wg = blockIdx.x * 4 + wave;    // global wave id
    if (wg * 16 >= N_DST) return;            // no barriers below: safe
    const int rw0 = wg * 16;                 // wave's first row

    // ---- gather: 4 iterations x 4 rows (one row per 16-lane quad)
#pragma unroll
    for (int i = 0; i < 4; i++) {
        int rl = wave * 16 + i * 4 + quad;          // local row 0..63
        int row = blockIdx.x * 64 + rl;
        int start = row_start[row];
        int deg = row_start[row + 1] - start;
        int nfull = deg & ~7;
        float a[8] = {0.f, 0.f, 0.f, 0.f, 0.f, 0.f, 0.f, 0.f};
        for (int base = 0; base < nfull; base += 8) {
#pragma unroll
            for (int t = 0; t < 8; t++) {
                int s = edge_src[start + base + t];   // same addr: HW bcast
                uint4 u = *(const uint4*)(mir + (size_t)s * 128 + lr * 8);
                a[0] += __uint_as_float(u.x << 16);
                a[1] += __uint_as_float(u.x & 0xffff0000u);
                a[2] += __uint_as_float(u.y << 16);
                a[3] += __uint_as_float(u.y & 0xffff0000u);
                a[4] += __uint_as_float(u.z << 16);
                a[5] += __uint_as_float(u.z & 0xffff0000u);
                a[6] += __uint_as_float(u.w << 16);
                a[7] += __uint_as_float(u.w & 0xffff0000u);
            }
        }
        if (nfull < deg) {
#pragma unroll
            for (int t = 0; t < 8; t++) {
                int s = edge_src[start + min(nfull + t, deg - 1)];
                uint4 u = *(const uint4*)(mir + (size_t)s * 128 + lr * 8);
                float m = ((nfull + t) < deg) ? 1.f : 0.f;
                a[0] = fmaf(__uint_as_float(u.x << 16), m, a[0]);
                a[1] = fmaf(__uint_as_float(u.x & 0xffff0000u), m, a[1]);
                a[2] = fmaf(__uint_as_float(u.y << 16), m, a[2]);
                a[3] = fmaf(__uint_as_float(u.y & 0xffff0000u), m, a[3]);
                a[4] = fmaf(__uint_as_float(u.z << 16), m, a[4]);
                a[5] = fmaf(__uint_as_float(u.z & 0xffff0000u), m, a[5]);
                a[6] = fmaf(__uint_as_float(u.w << 16), m, a[6]);
                a[7] = fmaf(__uint_as_float(u.w & 0xffff0000u), m, a[7]);
            }
        }
        float inv = 1.0f / fmaxf((float)deg, 1.0f);
        uint4 o;
        o.x = pk2(a[0] * inv, a[1] * inv);
        o.y = pk2(a[2] * inv, a[3] * inv);
        o.z = pk2(a[4] * inv, a[5] * inv);
        o.w = pk2(a[6] * inv, a[7] * inv);
        // XOR swizzle (bits 4-6) -> max 2-way conflict on the frag reads
        int ba = (rl * 256 + lr * 16) ^ ((rl & 7) << 4);
        *(uint4*)(hN + ba) = o;
    }

    // ---- read back own h_N fragments (in-wave LDS dep; compiler waits)
    s8v an[4];
    {
        int rl = wave * 16 + lr;
#pragma unroll
        for (int s = 0; s < 4; s++) {
            int ba = (rl * 256 + s * 64 + quad * 16) ^ ((rl & 7) << 4);
            an[s] = *(const s8v*)(hN + ba);
        }
    }

    // ---- h_dst loads + convert to bf16 A fragments
    const int r0 = rw0 + lr;
    const float* p0 = h_dst + (size_t)r0 * D + quad * 8;
    float4 x0[4], y0[4];
#pragma unroll
    for (int s = 0; s < 4; s++) {
        x0[s] = *(const float4*)(p0 + s * 32);
        y0[s] = *(const float4*)(p0 + s * 32 + 4);
    }
    s8v af0[4];
#pragma unroll
    for (int s = 0; s < 4; s++) {
        unsigned short u0[8];
        u0[0]=f2bf(x0[s].x); u0[1]=f2bf(x0[s].y); u0[2]=f2bf(x0[s].z); u0[3]=f2bf(x0[s].w);
        u0[4]=f2bf(y0[s].x); u0[5]=f2bf(y0[s].y); u0[6]=f2bf(y0[s].z); u0[7]=f2bf(y0[s].w);
        af0[s] = *(s8v*)u0;
    }

    f32x4 acc[8];
#pragma unroll
    for (int t = 0; t < 8; t++) acc[t] = (f32x4){0.f, 0.f, 0.f, 0.f};

    // ---- MFMA: K=0..127 from h_dst frags, K=128..255 from h_N frags
#pragma unroll
    for (int s = 0; s < 8; s++) {
        s8v a0 = (s < 4) ? af0[s] : an[s - 4];
#pragma unroll
        for (int t = 0; t < 8; t++) {
            s8v bf = *(const s8v*)(Bp + ((size_t)(s * 8 + t) * 64 + lane) * 8);
            acc[t] = __builtin_amdgcn_mfma_f32_16x16x32_bf16(a0, bf, acc[t], 0, 0, 0);
        }
    }

    // ---- epilogue (N_DST % 16 == 0: wave's rows all valid)
#pragma unroll
    for (int t = 0; t < 8; t++) {
        float bv = bias[t * 16 + lr];
#pragma unroll
        for (int r = 0; r < 4; r++) {
            int row = rw0 + quad * 4 + r;
            out[(size_t)row * D + t * 16 + lr] = acc[t][r] + bv;
        }
    }
}

extern "C" void kernel_launch(void* const* d_in, const int* in_sizes, int n_in,
                              void* d_out, int out_size, void* d_ws, size_t ws_size,
                              hipStream_t stream) {
    const float* h_src  = (const float*)d_in[0];
    const float* h_dst  = (const float*)d_in[1];
    const int* src_idx  = (const int*)d_in[2];
    const int* dst_idx  = (const int*)d_in[3];
    const float* W      = (const float*)d_in[4];
    const float* b      = (const float*)d_in[5];
    float* out = (float*)d_out;

    // Workspace: Bp | CSR ints | edge_src | dense bf16 mirror (~29.5 MB)
    unsigned short* Bp = (unsigned short*)d_ws;         // 32768 u16 = 64 KB
    int* ws_i          = (int*)((char*)d_ws + 65536);
    int* row_start     = ws_i;                          // N_DST+1
    int* cursor        = row_start + (N_DST + 1);       // N_DST
    int* counts        = cursor + N_DST;                // N_DST
    int* block_sums    = counts + N_DST;                // N_SCAN_BLOCKS
    int* edge_src      = block_sums + N_SCAN_BLOCKS;    // N_EDGES

    size_t int_bytes = (size_t)(N_DST + 1 + N_DST + N_DST + N_SCAN_BLOCKS
                                + N_EDGES) * 4;
    size_t mir_off   = (65536 + int_bytes + 255) & ~(size_t)255;
    unsigned short* mir = (unsigned short*)((char*)d_ws + mir_off);

    hipMemsetAsync(counts, 0, (size_t)N_DST * sizeof(int), stream);

    // critical path: hist -> scan -> add -> scatter
    hist_kernel<<<(N_EDGES + 255) / 256, 256, 0, stream>>>(dst_idx, counts);
    scan_blocks<<<N_SCAN_BLOCKS, 256, 0, stream>>>(counts, row_start, block_sums);
    add_offsets<<<(N_DST + 255) / 256, 256, 0, stream>>>(row_start, block_sums, cursor);

    // scatter (latency-bound) overlapped with cvt+packW (BW-bound)
    scatter_cvt<<<SCAT_BLOCKS + CVT_BLOCKS + PACKW_BLOCKS, 256, 0, stream>>>(
        src_idx, dst_idx, cursor, edge_src,
        h_src, (unsigned int*)mir, W, Bp);

    fused_ag<<<(N_DST + 63) / 64, 256, 0, stream>>>(
        h_dst, mir, row_start, edge_src, Bp, b, out);
}